// Round 17
// baseline (2716.256 us; speedup 1.0000x reference)
//
#include <hip/hip_runtime.h>
#include <hip/hip_bf16.h>
#include <math.h>

#define NN 1024
#define ND 256

// ROOT CAUSE (found R16, present since R0): "if (t < 1280)" guards with
// blockDim=1024 left muT[1024..1279] (cluster k=4's mu column) as garbage LDS.
// Fixed with strided loops at all three 1280-element sites.

__device__ __forceinline__ float wave_reduce_sum(float v) {
#pragma unroll
    for (int off = 32; off > 0; off >>= 1) v += __shfl_down(v, off, 64);
    return v;
}

__global__ void zero_k(float* __restrict__ out) {
    int i = blockIdx.x * 1024 + threadIdx.x;
    out[(size_t)i * 8] = 0.f;
}

// ---------------- fused attention: QL/KL on the fly, flash softmax, f -> ch0 ----------------
__global__ __launch_bounds__(512) void attn_k(
    const float* __restrict__ query, const float* __restrict__ key,
    const float* __restrict__ value, const float* __restrict__ W0,
    const float* __restrict__ b0v, const float* __restrict__ W1,
    const float* __restrict__ b1v, const float* __restrict__ lamda,
    float* __restrict__ out)
{
    int bh = blockIdx.x; int b = bh >> 3, h = bh & 7;
    int t = threadIdx.x;
    int q = blockIdx.y * 512 + t;
    const float scale = 0.17677669529663687f;
    __shared__ float kv[128 * 32];
    __shared__ float vv[128];
    float qreg[32];
    {
        const float* qrow = query + ((size_t)b * NN + q) * ND;
        const float* W0h = W0 + (size_t)h * 32 * ND;
#pragma unroll 2
        for (int j = 0; j < 32; j++) {
            const float* wr = W0h + j * ND;
            float s = 0.f;
            for (int c = 0; c < ND; c += 4) {
                float4 qv = *(const float4*)&qrow[c];
                float4 wv = *(const float4*)&wr[c];
                s += qv.x * wv.x + qv.y * wv.y + qv.z * wv.z + qv.w * wv.w;
            }
            qreg[j] = s + b0v[h * 32 + j];
        }
    }
    const float* W1h = W1 + (size_t)h * 32 * ND;
    float m = -3.0e38f, l = 0.f, acc = 0.f, wsacc = 0.f;
    for (int kt = 0; kt < 8; kt++) {
        __syncthreads();
        {
            int dc = t & 31, rb = t >> 5;
            const float* wr = W1h + dc * ND;
            float bb = b1v[h * 32 + dc];
#pragma unroll 2
            for (int p = 0; p < 8; p++) {
                int r = rb * 8 + p;
                const float* krow = key + ((size_t)b * NN + kt * 128 + r) * ND;
                float s = 0.f;
                for (int c = 0; c < ND; c += 4) {
                    float4 kk = *(const float4*)&krow[c];
                    float4 wv = *(const float4*)&wr[c];
                    s += kk.x * wv.x + kk.y * wv.y + kk.z * wv.z + kk.w * wv.w;
                }
                kv[r * 32 + dc] = s + bb;
            }
            if (t < 128) vv[t] = value[(size_t)b * NN + kt * 128 + t];
        }
        __syncthreads();
        for (int r = 0; r < 128; r++) {
            const float* kr = &kv[r * 32];
            float dot = 0.f;
#pragma unroll
            for (int j4 = 0; j4 < 8; j4++) {
                float4 kx = *(const float4*)&kr[j4 * 4];
                dot += qreg[j4*4+0]*kx.x + qreg[j4*4+1]*kx.y + qreg[j4*4+2]*kx.z + qreg[j4*4+3]*kx.w;
            }
            wsacc += dot * vv[r];
            float s = dot * scale;
            float nm = fmaxf(m, s);
            float p = expf(s - nm);
            float cor = expf(m - nm);
            l = l * cor + p;
            acc = acc * cor + p * vv[r];
            m = nm;
        }
    }
    float part = acc / l;
    float whole = fmaxf(wsacc * scale * (1.0f / 1024.0f), 0.f);
    float lam = lamda[0];
    float f = ((1.f - lam) * part + lam * whole) * 0.125f;
    atomicAdd(&out[((size_t)b * NN + q) * 8], f);
}

// ---------------- pmms1 EM -> P1 -> pmms2 -> P2 -> nw1/nw2 convs (fp32) ----------------
__global__ __launch_bounds__(1024) void mega_k(
    const float* __restrict__ query,
    const float* __restrict__ mu0a, const float* __restrict__ mu0b,
    const float* __restrict__ w1a, const float* __restrict__ b1a,
    const float* __restrict__ ga,  const float* __restrict__ bea,
    const float* __restrict__ w2a, const float* __restrict__ b2a,
    const float* __restrict__ w1b, const float* __restrict__ b1b,
    const float* __restrict__ gb,  const float* __restrict__ beb,
    const float* __restrict__ w2b, const float* __restrict__ b2b,
    float* __restrict__ out)
{
    __shared__ float sm[12890];
    float* muT    = sm;            // [k*256+c], 1280
    float* z_sT   = sm + 1280;     // [k*1024+n], 5120
    float* red_s  = sm + 6400;     // 5120
    float* mn_s   = sm + 11520;    // 1280 (later mu2s)
    float* wsum_s = sm + 12800;    // 80
    float* inv_s  = sm + 12880;    // 5
    float* nrm_s  = sm + 12885;    // 5
    int b = blockIdx.x, t = threadIdx.x;
    const float* qbase = query + (size_t)b * NN * ND;
    // FIX: strided loop covers all 1280 entries (blockDim is 1024)
    for (int idx = t; idx < 1280; idx += 1024)
        muT[idx] = mu0a[(idx & 255) * 5 + (idx >> 8)];
    __syncthreads();
    int wave = t >> 6, lane = t & 63;
    const float* qrow = qbase + (size_t)t * ND;
    int c = t & 255, chunk = t >> 8;
    for (int stage = 0; stage < 10; stage++) {
        float lg[5] = {0.f, 0.f, 0.f, 0.f, 0.f};
        for (int c4 = 0; c4 < 256; c4 += 4) {
            float4 qv = *(const float4*)&qrow[c4];
#pragma unroll
            for (int k = 0; k < 5; k++) {
                float4 mv = *(const float4*)&muT[k * 256 + c4];
                lg[k] += qv.x * mv.x + qv.y * mv.y + qv.z * mv.z + qv.w * mv.w;
            }
        }
        float mx = lg[0];
#pragma unroll
        for (int k = 1; k < 5; k++) mx = fmaxf(mx, lg[k]);
        float e[5], ssum = 0.f;
#pragma unroll
        for (int k = 0; k < 5; k++) { e[k] = expf(20.0f * (lg[k] - mx)); ssum += e[k]; }
        float is = 1.0f / ssum;
        float z[5];
#pragma unroll
        for (int k = 0; k < 5; k++) { z[k] = e[k] * is; z_sT[k * 1024 + t] = z[k]; }
#pragma unroll
        for (int k = 0; k < 5; k++) {
            float wsv = wave_reduce_sum(z[k]);
            if (lane == 0) wsum_s[wave * 5 + k] = wsv;
        }
        __syncthreads();
        if (t < 5) {
            float s2 = 0.f;
            for (int w = 0; w < 16; w++) s2 += wsum_s[w * 5 + t];
            inv_s[t] = 1.0f / (1e-6f + s2);
        }
        __syncthreads();
        float pa[5] = {0.f, 0.f, 0.f, 0.f, 0.f};
        for (int n4 = 0; n4 < 256; n4 += 4) {
            int n = chunk * 256 + n4;
            float q0 = qbase[(size_t)(n + 0) * ND + c];
            float q1 = qbase[(size_t)(n + 1) * ND + c];
            float q2 = qbase[(size_t)(n + 2) * ND + c];
            float q3 = qbase[(size_t)(n + 3) * ND + c];
#pragma unroll
            for (int k = 0; k < 5; k++) {
                float4 zv = *(const float4*)&z_sT[k * 1024 + n];
                pa[k] += q0 * zv.x + q1 * zv.y + q2 * zv.z + q3 * zv.w;
            }
        }
#pragma unroll
        for (int k = 0; k < 5; k++) red_s[(c * 5 + k) * 4 + chunk] = pa[k];
        __syncthreads();
        // FIX: strided loop (1280 entries)
        for (int idx = t; idx < 1280; idx += 1024) {
            float s3 = red_s[idx * 4] + red_s[idx * 4 + 1] + red_s[idx * 4 + 2] + red_s[idx * 4 + 3];
            mn_s[idx] = s3 * inv_s[idx % 5];
        }
        __syncthreads();
        if (t < 256) {
            float sq[5];
#pragma unroll
            for (int k = 0; k < 5; k++) { float v = mn_s[t * 5 + k]; sq[k] = v * v; }
#pragma unroll
            for (int k = 0; k < 5; k++) {
                float wsv = wave_reduce_sum(sq[k]);
                if (lane == 0) wsum_s[wave * 5 + k] = wsv;
            }
        }
        __syncthreads();
        if (t < 5) {
            float s4 = 0.f;
            for (int w = 0; w < 4; w++) s4 += wsum_s[w * 5 + t];
            nrm_s[t] = 1.0f / (1e-6f + sqrtf(s4));
        }
        __syncthreads();
        // FIX: strided loop (1280 entries)
        for (int idx = t; idx < 1280; idx += 1024)
            muT[idx] = mn_s[(idx & 255) * 5 + (idx >> 8)] * nrm_s[idx >> 8];
        __syncthreads();
    }
    // ======== P1 (no kappa) ========
    float p1r[5];
    {
        float lg[5] = {0.f, 0.f, 0.f, 0.f, 0.f};
        for (int c4 = 0; c4 < 256; c4 += 4) {
            float4 qv = *(const float4*)&qrow[c4];
#pragma unroll
            for (int k = 0; k < 5; k++) {
                float4 mv = *(const float4*)&muT[k * 256 + c4];
                lg[k] += qv.x * mv.x + qv.y * mv.y + qv.z * mv.z + qv.w * mv.w;
            }
        }
        float mx = lg[0];
#pragma unroll
        for (int k = 1; k < 5; k++) mx = fmaxf(mx, lg[k]);
        float e[5], ssum = 0.f;
#pragma unroll
        for (int k = 0; k < 5; k++) { e[k] = expf(lg[k] - mx); ssum += e[k]; }
        float is = 1.0f / ssum;
#pragma unroll
        for (int k = 0; k < 5; k++) p1r[k] = e[k] * is;
    }
    // ======== pmms2 on m1 (in muT), n=5, k=2 ========
    float* wredB = sm + 12800;
    float* znB   = sm + 12844;
    float* nrmB  = sm + 12856;
    float* mu2s  = sm + 11520;
    float ndB[5] = {0,0,0,0,0}, muB[2] = {0,0};
    __syncthreads();
    if (t < 256) {
#pragma unroll
        for (int n = 0; n < 5; n++) ndB[n] = muT[n * 256 + t];
        muB[0] = mu0b[t * 2 + 0];
        muB[1] = mu0b[t * 2 + 1];
    }
    for (int stage = 0; stage < 10; stage++) {
        float nm0 = 0.f, nm1 = 0.f;
        if (t < 256) {
            float lgp[10];
#pragma unroll
            for (int n = 0; n < 5; n++) {
                lgp[n * 2 + 0] = ndB[n] * muB[0];
                lgp[n * 2 + 1] = ndB[n] * muB[1];
            }
#pragma unroll
            for (int i = 0; i < 10; i++) {
                float s = wave_reduce_sum(lgp[i]);
                if (lane == 0) wredB[wave * 10 + i] = s;
            }
        }
        __syncthreads();
        if (t == 0) {
            float cs0 = 0.f, cs1 = 0.f;
            float zt[10];
            for (int n = 0; n < 5; n++) {
                float a0 = 20.0f * (wredB[n * 2] + wredB[10 + n * 2] + wredB[20 + n * 2] + wredB[30 + n * 2]);
                float a1 = 20.0f * (wredB[n * 2 + 1] + wredB[10 + n * 2 + 1] + wredB[20 + n * 2 + 1] + wredB[30 + n * 2 + 1]);
                float mx = fmaxf(a0, a1);
                float e0 = expf(a0 - mx), e1 = expf(a1 - mx);
                float inv = 1.0f / (e0 + e1);
                zt[n * 2] = e0 * inv; zt[n * 2 + 1] = e1 * inv;
                cs0 += zt[n * 2]; cs1 += zt[n * 2 + 1];
            }
            float i0 = 1.0f / (1e-6f + cs0), i1 = 1.0f / (1e-6f + cs1);
            for (int n = 0; n < 5; n++) {
                znB[n * 2] = zt[n * 2] * i0;
                znB[n * 2 + 1] = zt[n * 2 + 1] * i1;
            }
        }
        __syncthreads();
        if (t < 256) {
#pragma unroll
            for (int n = 0; n < 5; n++) {
                nm0 += ndB[n] * znB[n * 2];
                nm1 += ndB[n] * znB[n * 2 + 1];
            }
            float s0 = wave_reduce_sum(nm0 * nm0);
            float s1 = wave_reduce_sum(nm1 * nm1);
            if (lane == 0) { wredB[wave * 10 + 0] = s0; wredB[wave * 10 + 1] = s1; }
        }
        __syncthreads();
        if (t < 2) nrmB[t] = 1.0f / (1e-6f + sqrtf(wredB[t] + wredB[10 + t] + wredB[20 + t] + wredB[30 + t]));
        __syncthreads();
        if (t < 256) { muB[0] = nm0 * nrmB[0]; muB[1] = nm1 * nrmB[1]; }
        __syncthreads();
    }
    if (t < 256) { mu2s[t * 2] = muB[0]; mu2s[t * 2 + 1] = muB[1]; }
    __syncthreads();
    // ======== P2 (no kappa) ========
    float p2r[2];
    {
        float l0 = 0.f, l1 = 0.f;
        for (int c4 = 0; c4 < 256; c4 += 4) {
            float4 qv = *(const float4*)&qrow[c4];
            l0 += qv.x * mu2s[c4 * 2] + qv.y * mu2s[(c4 + 1) * 2] + qv.z * mu2s[(c4 + 2) * 2] + qv.w * mu2s[(c4 + 3) * 2];
            l1 += qv.x * mu2s[c4 * 2 + 1] + qv.y * mu2s[(c4 + 1) * 2 + 1] + qv.z * mu2s[(c4 + 2) * 2 + 1] + qv.w * mu2s[(c4 + 3) * 2 + 1];
        }
        float mx = fmaxf(l0, l1);
        float e0 = expf(l0 - mx), e1 = expf(l1 - mx);
        float inv = 1.0f / (e0 + e1);
        p2r[0] = e0 * inv; p2r[1] = e1 * inv;
    }
    // ======== conv gates ========
    float* img  = sm;
    float* mid  = sm + 1156;
    float* w1sA = sm + 2312;   float* w2sA = sm + 2456;
    float* bsA  = sm + 2600;   float* gsA  = sm + 2616;   float* besA = sm + 2632;  float* b2A = sm + 2648;
    float* w1sB = sm + 2656;   float* w2sB = sm + 2800;
    float* bsB  = sm + 2944;   float* gsB  = sm + 2960;   float* besB = sm + 2976;  float* b2B = sm + 2992;
    __syncthreads();
    for (int idx = t; idx < 2312; idx += 1024) sm[idx] = 0.f;
    if (t < 144) { w1sA[t] = w1a[t]; w2sA[t] = w2a[t]; }
    if (t >= 256 && t < 272) { int y = t - 256; bsA[y] = b1a[y]; gsA[y] = ga[y]; besA[y] = bea[y]; }
    if (t >= 288 && t < 432) { int y = t - 288; w1sB[y] = w1b[y]; w2sB[y] = w2b[y]; }
    if (t >= 448 && t < 464) { int y = t - 448; bsB[y] = b1b[y]; gsB[y] = gb[y]; besB[y] = beb[y]; }
    if (t == 512) b2A[0] = b2a[0];
    if (t == 513) b2B[0] = b2b[0];
    int i = t >> 5, j = t & 31;
    int n = i * 32 + j;
    const float bninv = rsqrtf(1.0f + 1e-5f);
#pragma unroll 1
    for (int ch = 0; ch < 7; ch++) {
        float xv   = (ch < 5) ? p1r[ch] : p2r[ch - 5];
        float* w1s = (ch < 5) ? w1sA : w1sB;
        float* w2s = (ch < 5) ? w2sA : w2sB;
        float* bs  = (ch < 5) ? bsA  : bsB;
        float* gs  = (ch < 5) ? gsA  : gsB;
        float* bes = (ch < 5) ? besA : besB;
        __syncthreads();
        img[(i + 1) * 34 + (j + 1)] = xv;
        __syncthreads();
        float b2v = (ch < 5) ? b2A[0] : b2B[0];
        float acc2 = 0.f;
        for (int oc = 0; oc < 16; oc++) {
            float a = 0.f;
#pragma unroll
            for (int dy = 0; dy < 3; dy++)
#pragma unroll
                for (int dx = 0; dx < 3; dx++)
                    a += w1s[oc * 9 + dy * 3 + dx] * img[(i + dy) * 34 + (j + dx)];
            a += bs[oc];
            a = gs[oc] * (a * bninv) + bes[oc];
            a = fmaxf(a, 0.f);
            __syncthreads();
            mid[(i + 1) * 34 + (j + 1)] = a;
            __syncthreads();
#pragma unroll
            for (int dy = 0; dy < 3; dy++)
#pragma unroll
                for (int dx = 0; dx < 3; dx++)
                    acc2 += w2s[oc * 9 + dy * 3 + dx] * mid[(i + dy) * 34 + (j + dx)];
        }
        acc2 += b2v;
        float sig = 1.0f / (1.0f + expf(-acc2));
        out[((size_t)(b * 1024 + n)) * 8 + 1 + ch] = xv * sig;
    }
}

extern "C" void kernel_launch(void* const* d_in, const int* in_sizes, int n_in,
                              void* d_out, int out_size, void* d_ws, size_t ws_size,
                              hipStream_t stream) {
    const float* query = (const float*)d_in[0];
    const float* key   = (const float*)d_in[1];
    const float* value = (const float*)d_in[2];
    const float* lamda = (const float*)d_in[3];
    const float* W0 = (const float*)d_in[4];
    const float* b0 = (const float*)d_in[5];
    const float* W1 = (const float*)d_in[6];
    const float* b1 = (const float*)d_in[7];
    const float* mu_a = (const float*)d_in[8];
    const float* mu_b = (const float*)d_in[9];
    const float* nw1_w1 = (const float*)d_in[10];
    const float* nw1_b1 = (const float*)d_in[11];
    const float* nw1_g  = (const float*)d_in[12];
    const float* nw1_be = (const float*)d_in[13];
    const float* nw1_w2 = (const float*)d_in[14];
    const float* nw1_b2 = (const float*)d_in[15];
    const float* nw2_w1 = (const float*)d_in[16];
    const float* nw2_b1 = (const float*)d_in[17];
    const float* nw2_g  = (const float*)d_in[18];
    const float* nw2_be = (const float*)d_in[19];
    const float* nw2_w2 = (const float*)d_in[20];
    const float* nw2_b2 = (const float*)d_in[21];
    float* out = (float*)d_out;
    (void)d_ws; (void)ws_size;

    zero_k<<<16, 1024, 0, stream>>>(out);
    attn_k<<<dim3(128, 2), 512, 0, stream>>>(query, key, value, W0, b0, W1, b1, lamda, out);
    mega_k<<<16, 1024, 0, stream>>>(query, mu_a, mu_b,
                                    nw1_w1, nw1_b1, nw1_g, nw1_be, nw1_w2, nw1_b2,
                                    nw2_w1, nw2_b1, nw2_g, nw2_be, nw2_w2, nw2_b2, out);
}

// Round 18
// 1209.224 us; speedup vs baseline: 2.2463x; 2.2463x over previous
//
#include <hip/hip_runtime.h>
#include <hip/hip_bf16.h>
#include <math.h>

#define NN 1024
#define ND 256

typedef __hip_bfloat16 bf;
__device__ __forceinline__ float bf2f(bf h) { return __bfloat162float(h); }

__device__ __forceinline__ float wave_reduce_sum(float v) {
#pragma unroll
    for (int off = 32; off > 0; off >>= 1) v += __shfl_down(v, off, 64);
    return v;
}

__global__ void zero_k(float* __restrict__ out) {
    int i = blockIdx.x * 1024 + threadIdx.x;
    out[(size_t)i * 8] = 0.f;
}

// ---------------- QL = query@W0^T+b0 ; KL = key@W1^T+b1 (bf16 out to ws) ----------------
__global__ __launch_bounds__(256) void gemm_k(
    const float* __restrict__ Aq, const float* __restrict__ Ak,
    const float* __restrict__ W0, const float* __restrict__ b0v,
    const float* __restrict__ W1, const float* __restrict__ b1v,
    bf* __restrict__ QL, bf* __restrict__ KL)
{
    const float* A; const float* Bw; const float* bias; bf* C;
    if (blockIdx.z == 0) { A = Aq; Bw = W0; bias = b0v; C = QL; }
    else                 { A = Ak; Bw = W1; bias = b1v; C = KL; }
    __shared__ float As[16][65];
    __shared__ float Bs[16][65];
    const int t = threadIdx.x;
    const int m0 = blockIdx.x * 64;
    const int n0 = blockIdx.y * 64;
    const int lm = t >> 2;
    const int lk = (t & 3) * 4;
    const int tr = (t >> 4) * 4;
    const int tc = (t & 15) * 4;
    float acc[4][4] = {};
    for (int k0 = 0; k0 < 256; k0 += 16) {
        float4 a4 = *(const float4*)(A + (size_t)(m0 + lm) * 256 + k0 + lk);
        float4 b4 = *(const float4*)(Bw + (size_t)(n0 + lm) * 256 + k0 + lk);
        __syncthreads();
        As[lk + 0][lm] = a4.x; As[lk + 1][lm] = a4.y; As[lk + 2][lm] = a4.z; As[lk + 3][lm] = a4.w;
        Bs[lk + 0][lm] = b4.x; Bs[lk + 1][lm] = b4.y; Bs[lk + 2][lm] = b4.z; Bs[lk + 3][lm] = b4.w;
        __syncthreads();
#pragma unroll
        for (int k = 0; k < 16; k++) {
            float av[4], bv[4];
#pragma unroll
            for (int i = 0; i < 4; i++) av[i] = As[k][tr + i];
#pragma unroll
            for (int j = 0; j < 4; j++) bv[j] = Bs[k][tc + j];
#pragma unroll
            for (int i = 0; i < 4; i++)
#pragma unroll
                for (int j = 0; j < 4; j++) acc[i][j] += av[i] * bv[j];
        }
    }
#pragma unroll
    for (int i = 0; i < 4; i++) {
        ushort4 pk;
        bf h0 = __float2bfloat16(acc[i][0] + bias[n0 + tc + 0]);
        bf h1 = __float2bfloat16(acc[i][1] + bias[n0 + tc + 1]);
        bf h2 = __float2bfloat16(acc[i][2] + bias[n0 + tc + 2]);
        bf h3 = __float2bfloat16(acc[i][3] + bias[n0 + tc + 3]);
        pk.x = *(unsigned short*)&h0; pk.y = *(unsigned short*)&h1;
        pk.z = *(unsigned short*)&h2; pk.w = *(unsigned short*)&h3;
        *(ushort4*)&C[(size_t)(m0 + tr + i) * 256 + n0 + tc] = pk;
    }
}

// ---------------- flash attention from materialized bf16 QL/KL ----------------
// q.key_global = (1/1024) sum_n value[n]*(q.k_n); f -> atomicAdd out ch0.
__global__ __launch_bounds__(256) void attn2_k(
    const bf* __restrict__ QL, const bf* __restrict__ KL,
    const float* __restrict__ value, const float* __restrict__ lamda,
    float* __restrict__ out)
{
    int bh = blockIdx.x; int b = bh >> 3, h = bh & 7;
    int t = threadIdx.x;
    int q = blockIdx.y * 256 + t;
    const float scale = 0.17677669529663687f;
    __shared__ float kv[128 * 32];
    __shared__ float vv[128];
    float qreg[32];
    {
        const bf* qrow = QL + ((size_t)b * NN + q) * ND + h * 32;
#pragma unroll
        for (int p = 0; p < 4; p++) {
            float4 raw = ((const float4*)qrow)[p];
            const bf* hb = (const bf*)&raw;
#pragma unroll
            for (int j = 0; j < 8; j++) qreg[p * 8 + j] = bf2f(hb[j]);
        }
    }
    float m = -3.0e38f, l = 0.f, acc = 0.f, wsacc = 0.f;
    for (int kt = 0; kt < 8; kt++) {
        __syncthreads();
#pragma unroll
        for (int i = 0; i < 2; i++) {
            int s = t + i * 256;               // 512 slots; row = s>>2, seg = s&3
            int row = s >> 2, seg = s & 3;
            float4 raw = *(const float4*)&KL[((size_t)b * NN + kt * 128 + row) * ND + h * 32 + seg * 8];
            const bf* hb = (const bf*)&raw;
#pragma unroll
            for (int j = 0; j < 8; j++) kv[row * 32 + seg * 8 + j] = bf2f(hb[j]);
        }
        if (t < 128) vv[t] = value[(size_t)b * NN + kt * 128 + t];
        __syncthreads();
        for (int r = 0; r < 128; r++) {
            const float* kr = &kv[r * 32];
            float dot = 0.f;
#pragma unroll
            for (int j4 = 0; j4 < 8; j4++) {
                float4 kx = *(const float4*)&kr[j4 * 4];
                dot += qreg[j4*4+0]*kx.x + qreg[j4*4+1]*kx.y + qreg[j4*4+2]*kx.z + qreg[j4*4+3]*kx.w;
            }
            wsacc += dot * vv[r];
            float s = dot * scale;
            float nm = fmaxf(m, s);
            float p = expf(s - nm);
            float cor = expf(m - nm);
            l = l * cor + p;
            acc = acc * cor + p * vv[r];
            m = nm;
        }
    }
    float part = acc / l;
    float whole = fmaxf(wsacc * scale * (1.0f / 1024.0f), 0.f);
    float lam = lamda[0];
    float f = ((1.f - lam) * part + lam * whole) * 0.125f;
    atomicAdd(&out[((size_t)b * NN + q) * 8], f);
}

// ---------------- mega_k: UNCHANGED from the R17 passing version ----------------
__global__ __launch_bounds__(1024) void mega_k(
    const float* __restrict__ query,
    const float* __restrict__ mu0a, const float* __restrict__ mu0b,
    const float* __restrict__ w1a, const float* __restrict__ b1a,
    const float* __restrict__ ga,  const float* __restrict__ bea,
    const float* __restrict__ w2a, const float* __restrict__ b2a,
    const float* __restrict__ w1b, const float* __restrict__ b1b,
    const float* __restrict__ gb,  const float* __restrict__ beb,
    const float* __restrict__ w2b, const float* __restrict__ b2b,
    float* __restrict__ out)
{
    __shared__ float sm[12890];
    float* muT    = sm;
    float* z_sT   = sm + 1280;
    float* red_s  = sm + 6400;
    float* mn_s   = sm + 11520;
    float* wsum_s = sm + 12800;
    float* inv_s  = sm + 12880;
    float* nrm_s  = sm + 12885;
    int b = blockIdx.x, t = threadIdx.x;
    const float* qbase = query + (size_t)b * NN * ND;
    for (int idx = t; idx < 1280; idx += 1024)
        muT[idx] = mu0a[(idx & 255) * 5 + (idx >> 8)];
    __syncthreads();
    int wave = t >> 6, lane = t & 63;
    const float* qrow = qbase + (size_t)t * ND;
    int c = t & 255, chunk = t >> 8;
    for (int stage = 0; stage < 10; stage++) {
        float lg[5] = {0.f, 0.f, 0.f, 0.f, 0.f};
        for (int c4 = 0; c4 < 256; c4 += 4) {
            float4 qv = *(const float4*)&qrow[c4];
#pragma unroll
            for (int k = 0; k < 5; k++) {
                float4 mv = *(const float4*)&muT[k * 256 + c4];
                lg[k] += qv.x * mv.x + qv.y * mv.y + qv.z * mv.z + qv.w * mv.w;
            }
        }
        float mx = lg[0];
#pragma unroll
        for (int k = 1; k < 5; k++) mx = fmaxf(mx, lg[k]);
        float e[5], ssum = 0.f;
#pragma unroll
        for (int k = 0; k < 5; k++) { e[k] = expf(20.0f * (lg[k] - mx)); ssum += e[k]; }
        float is = 1.0f / ssum;
        float z[5];
#pragma unroll
        for (int k = 0; k < 5; k++) { z[k] = e[k] * is; z_sT[k * 1024 + t] = z[k]; }
#pragma unroll
        for (int k = 0; k < 5; k++) {
            float wsv = wave_reduce_sum(z[k]);
            if (lane == 0) wsum_s[wave * 5 + k] = wsv;
        }
        __syncthreads();
        if (t < 5) {
            float s2 = 0.f;
            for (int w = 0; w < 16; w++) s2 += wsum_s[w * 5 + t];
            inv_s[t] = 1.0f / (1e-6f + s2);
        }
        __syncthreads();
        float pa[5] = {0.f, 0.f, 0.f, 0.f, 0.f};
        for (int n4 = 0; n4 < 256; n4 += 4) {
            int n = chunk * 256 + n4;
            float q0 = qbase[(size_t)(n + 0) * ND + c];
            float q1 = qbase[(size_t)(n + 1) * ND + c];
            float q2 = qbase[(size_t)(n + 2) * ND + c];
            float q3 = qbase[(size_t)(n + 3) * ND + c];
#pragma unroll
            for (int k = 0; k < 5; k++) {
                float4 zv = *(const float4*)&z_sT[k * 1024 + n];
                pa[k] += q0 * zv.x + q1 * zv.y + q2 * zv.z + q3 * zv.w;
            }
        }
#pragma unroll
        for (int k = 0; k < 5; k++) red_s[(c * 5 + k) * 4 + chunk] = pa[k];
        __syncthreads();
        for (int idx = t; idx < 1280; idx += 1024) {
            float s3 = red_s[idx * 4] + red_s[idx * 4 + 1] + red_s[idx * 4 + 2] + red_s[idx * 4 + 3];
            mn_s[idx] = s3 * inv_s[idx % 5];
        }
        __syncthreads();
        if (t < 256) {
            float sq[5];
#pragma unroll
            for (int k = 0; k < 5; k++) { float v = mn_s[t * 5 + k]; sq[k] = v * v; }
#pragma unroll
            for (int k = 0; k < 5; k++) {
                float wsv = wave_reduce_sum(sq[k]);
                if (lane == 0) wsum_s[wave * 5 + k] = wsv;
            }
        }
        __syncthreads();
        if (t < 5) {
            float s4 = 0.f;
            for (int w = 0; w < 4; w++) s4 += wsum_s[w * 5 + t];
            nrm_s[t] = 1.0f / (1e-6f + sqrtf(s4));
        }
        __syncthreads();
        for (int idx = t; idx < 1280; idx += 1024)
            muT[idx] = mn_s[(idx & 255) * 5 + (idx >> 8)] * nrm_s[idx >> 8];
        __syncthreads();
    }
    float p1r[5];
    {
        float lg[5] = {0.f, 0.f, 0.f, 0.f, 0.f};
        for (int c4 = 0; c4 < 256; c4 += 4) {
            float4 qv = *(const float4*)&qrow[c4];
#pragma unroll
            for (int k = 0; k < 5; k++) {
                float4 mv = *(const float4*)&muT[k * 256 + c4];
                lg[k] += qv.x * mv.x + qv.y * mv.y + qv.z * mv.z + qv.w * mv.w;
            }
        }
        float mx = lg[0];
#pragma unroll
        for (int k = 1; k < 5; k++) mx = fmaxf(mx, lg[k]);
        float e[5], ssum = 0.f;
#pragma unroll
        for (int k = 0; k < 5; k++) { e[k] = expf(lg[k] - mx); ssum += e[k]; }
        float is = 1.0f / ssum;
#pragma unroll
        for (int k = 0; k < 5; k++) p1r[k] = e[k] * is;
    }
    float* wredB = sm + 12800;
    float* znB   = sm + 12844;
    float* nrmB  = sm + 12856;
    float* mu2s  = sm + 11520;
    float ndB[5] = {0,0,0,0,0}, muB[2] = {0,0};
    __syncthreads();
    if (t < 256) {
#pragma unroll
        for (int n = 0; n < 5; n++) ndB[n] = muT[n * 256 + t];
        muB[0] = mu0b[t * 2 + 0];
        muB[1] = mu0b[t * 2 + 1];
    }
    for (int stage = 0; stage < 10; stage++) {
        float nm0 = 0.f, nm1 = 0.f;
        if (t < 256) {
            float lgp[10];
#pragma unroll
            for (int n = 0; n < 5; n++) {
                lgp[n * 2 + 0] = ndB[n] * muB[0];
                lgp[n * 2 + 1] = ndB[n] * muB[1];
            }
#pragma unroll
            for (int i = 0; i < 10; i++) {
                float s = wave_reduce_sum(lgp[i]);
                if (lane == 0) wredB[wave * 10 + i] = s;
            }
        }
        __syncthreads();
        if (t == 0) {
            float cs0 = 0.f, cs1 = 0.f;
            float zt[10];
            for (int n = 0; n < 5; n++) {
                float a0 = 20.0f * (wredB[n * 2] + wredB[10 + n * 2] + wredB[20 + n * 2] + wredB[30 + n * 2]);
                float a1 = 20.0f * (wredB[n * 2 + 1] + wredB[10 + n * 2 + 1] + wredB[20 + n * 2 + 1] + wredB[30 + n * 2 + 1]);
                float mx = fmaxf(a0, a1);
                float e0 = expf(a0 - mx), e1 = expf(a1 - mx);
                float inv = 1.0f / (e0 + e1);
                zt[n * 2] = e0 * inv; zt[n * 2 + 1] = e1 * inv;
                cs0 += zt[n * 2]; cs1 += zt[n * 2 + 1];
            }
            float i0 = 1.0f / (1e-6f + cs0), i1 = 1.0f / (1e-6f + cs1);
            for (int n = 0; n < 5; n++) {
                znB[n * 2] = zt[n * 2] * i0;
                znB[n * 2 + 1] = zt[n * 2 + 1] * i1;
            }
        }
        __syncthreads();
        if (t < 256) {
#pragma unroll
            for (int n = 0; n < 5; n++) {
                nm0 += ndB[n] * znB[n * 2];
                nm1 += ndB[n] * znB[n * 2 + 1];
            }
            float s0 = wave_reduce_sum(nm0 * nm0);
            float s1 = wave_reduce_sum(nm1 * nm1);
            if (lane == 0) { wredB[wave * 10 + 0] = s0; wredB[wave * 10 + 1] = s1; }
        }
        __syncthreads();
        if (t < 2) nrmB[t] = 1.0f / (1e-6f + sqrtf(wredB[t] + wredB[10 + t] + wredB[20 + t] + wredB[30 + t]));
        __syncthreads();
        if (t < 256) { muB[0] = nm0 * nrmB[0]; muB[1] = nm1 * nrmB[1]; }
        __syncthreads();
    }
    if (t < 256) { mu2s[t * 2] = muB[0]; mu2s[t * 2 + 1] = muB[1]; }
    __syncthreads();
    float p2r[2];
    {
        float l0 = 0.f, l1 = 0.f;
        for (int c4 = 0; c4 < 256; c4 += 4) {
            float4 qv = *(const float4*)&qrow[c4];
            l0 += qv.x * mu2s[c4 * 2] + qv.y * mu2s[(c4 + 1) * 2] + qv.z * mu2s[(c4 + 2) * 2] + qv.w * mu2s[(c4 + 3) * 2];
            l1 += qv.x * mu2s[c4 * 2 + 1] + qv.y * mu2s[(c4 + 1) * 2 + 1] + qv.z * mu2s[(c4 + 2) * 2 + 1] + qv.w * mu2s[(c4 + 3) * 2 + 1];
        }
        float mx = fmaxf(l0, l1);
        float e0 = expf(l0 - mx), e1 = expf(l1 - mx);
        float inv = 1.0f / (e0 + e1);
        p2r[0] = e0 * inv; p2r[1] = e1 * inv;
    }
    float* img  = sm;
    float* mid  = sm + 1156;
    float* w1sA = sm + 2312;   float* w2sA = sm + 2456;
    float* bsA  = sm + 2600;   float* gsA  = sm + 2616;   float* besA = sm + 2632;  float* b2A = sm + 2648;
    float* w1sB = sm + 2656;   float* w2sB = sm + 2800;
    float* bsB  = sm + 2944;   float* gsB  = sm + 2960;   float* besB = sm + 2976;  float* b2B = sm + 2992;
    __syncthreads();
    for (int idx = t; idx < 2312; idx += 1024) sm[idx] = 0.f;
    if (t < 144) { w1sA[t] = w1a[t]; w2sA[t] = w2a[t]; }
    if (t >= 256 && t < 272) { int y = t - 256; bsA[y] = b1a[y]; gsA[y] = ga[y]; besA[y] = bea[y]; }
    if (t >= 288 && t < 432) { int y = t - 288; w1sB[y] = w1b[y]; w2sB[y] = w2b[y]; }
    if (t >= 448 && t < 464) { int y = t - 448; bsB[y] = b1b[y]; gsB[y] = gb[y]; besB[y] = beb[y]; }
    if (t == 512) b2A[0] = b2a[0];
    if (t == 513) b2B[0] = b2b[0];
    int i = t >> 5, j = t & 31;
    int n = i * 32 + j;
    const float bninv = rsqrtf(1.0f + 1e-5f);
#pragma unroll 1
    for (int ch = 0; ch < 7; ch++) {
        float xv   = (ch < 5) ? p1r[ch] : p2r[ch - 5];
        float* w1s = (ch < 5) ? w1sA : w1sB;
        float* w2s = (ch < 5) ? w2sA : w2sB;
        float* bs  = (ch < 5) ? bsA  : bsB;
        float* gs  = (ch < 5) ? gsA  : gsB;
        float* bes = (ch < 5) ? besA : besB;
        __syncthreads();
        img[(i + 1) * 34 + (j + 1)] = xv;
        __syncthreads();
        float b2v = (ch < 5) ? b2A[0] : b2B[0];
        float acc2 = 0.f;
        for (int oc = 0; oc < 16; oc++) {
            float a = 0.f;
#pragma unroll
            for (int dy = 0; dy < 3; dy++)
#pragma unroll
                for (int dx = 0; dx < 3; dx++)
                    a += w1s[oc * 9 + dy * 3 + dx] * img[(i + dy) * 34 + (j + dx)];
            a += bs[oc];
            a = gs[oc] * (a * bninv) + bes[oc];
            a = fmaxf(a, 0.f);
            __syncthreads();
            mid[(i + 1) * 34 + (j + 1)] = a;
            __syncthreads();
#pragma unroll
            for (int dy = 0; dy < 3; dy++)
#pragma unroll
                for (int dx = 0; dx < 3; dx++)
                    acc2 += w2s[oc * 9 + dy * 3 + dx] * mid[(i + dy) * 34 + (j + dx)];
        }
        acc2 += b2v;
        float sig = 1.0f / (1.0f + expf(-acc2));
        out[((size_t)(b * 1024 + n)) * 8 + 1 + ch] = xv * sig;
    }
}

extern "C" void kernel_launch(void* const* d_in, const int* in_sizes, int n_in,
                              void* d_out, int out_size, void* d_ws, size_t ws_size,
                              hipStream_t stream) {
    const float* query = (const float*)d_in[0];
    const float* key   = (const float*)d_in[1];
    const float* value = (const float*)d_in[2];
    const float* lamda = (const float*)d_in[3];
    const float* W0 = (const float*)d_in[4];
    const float* b0 = (const float*)d_in[5];
    const float* W1 = (const float*)d_in[6];
    const float* b1 = (const float*)d_in[7];
    const float* mu_a = (const float*)d_in[8];
    const float* mu_b = (const float*)d_in[9];
    const float* nw1_w1 = (const float*)d_in[10];
    const float* nw1_b1 = (const float*)d_in[11];
    const float* nw1_g  = (const float*)d_in[12];
    const float* nw1_be = (const float*)d_in[13];
    const float* nw1_w2 = (const float*)d_in[14];
    const float* nw1_b2 = (const float*)d_in[15];
    const float* nw2_w1 = (const float*)d_in[16];
    const float* nw2_b1 = (const float*)d_in[17];
    const float* nw2_g  = (const float*)d_in[18];
    const float* nw2_be = (const float*)d_in[19];
    const float* nw2_w2 = (const float*)d_in[20];
    const float* nw2_b2 = (const float*)d_in[21];
    float* out = (float*)d_out;

    // ws: QLb [0,8MB) + KLb [8,16MB) as bf16
    bf* QLb = (bf*)d_ws;
    bf* KLb = (bf*)((char*)d_ws + ((size_t)8 << 20));

    zero_k<<<16, 1024, 0, stream>>>(out);
    gemm_k<<<dim3(256, 4, 2), 256, 0, stream>>>(query, key, W0, b0, W1, b1, QLb, KLb);
    attn2_k<<<dim3(128, 4), 256, 0, stream>>>(QLb, KLb, value, lamda, out);
    mega_k<<<16, 1024, 0, stream>>>(query, mu_a, mu_b,
                                    nw1_w1, nw1_b1, nw1_g, nw1_be, nw1_w2, nw1_b2,
                                    nw2_w1, nw2_b1, nw2_g, nw2_be, nw2_w2, nw2_b2, out);
}